// Round 3
// baseline (5377.961 us; speedup 1.0000x reference)
//
#include <hip/hip_runtime.h>
#include <hip/hip_bf16.h>

// FFT-tiled conv: B=8, IMG=256, CIN=COUT=64, TILE=64, FFT=68, PAD=2.
// Frequency-domain per-tile conv via DFT-as-matmul, Hermitian half-spectrum
// (k2 in [0,35)), overlap-add gather. All fp32.
//
// Layouts (this round: all inter-stage tensors o/i-innermost where the
// producing block varies (n,o) per bin, so every global write is coalesced):
//   Y  [nl][r][i][k2c]            (k2c = 2*KH interleaved cplx)
//   X  [bin][i][nl][c]            bin = k1*KH+k2
//   K_t[bin][i][o][c]             one-time transposed kernel spectrum (78 MB)
//   O  [nl][k1][k2][o][c]
//   Z  [nl][k2][p][o][c]
//   S  [nl][p][q][o]

#define FFTN 68
#define KH   35
#define NTMAX 16
#define KT_FLOATS (68ull * KH * 64 * 64 * 2)   // 19,496,960

__global__ void k_twiddle(float* ws) {
    const float TWO_PI = 6.28318530717958647692f;
    int t = threadIdx.x;
    float* Wf = ws;
    for (int e = t; e < 68 * 64; e += 256) {
        int k = e >> 6, m = e & 63;
        int ph = (k * (m + 2)) % 68;
        float a = TWO_PI * (float)ph / 68.0f;
        Wf[2 * e]     = cosf(a);
        Wf[2 * e + 1] = -sinf(a);
    }
    float* Wi = ws + 8704;
    for (int e = t; e < 68 * 68; e += 256) {
        int p = e / 68, k = e % 68;
        int ph = (p * k) % 68;
        float a = TWO_PI * (float)ph / 68.0f;
        Wi[2 * e]     = cosf(a) / 68.0f;
        Wi[2 * e + 1] = sinf(a) / 68.0f;
    }
    float* Wg = ws + 17952;
    for (int e = t; e < 68 * KH; e += 256) {
        int q = e / KH, k2 = e % KH;
        int ph = (q * k2) % 68;
        float a = TWO_PI * (float)ph / 68.0f;
        float alpha = (k2 == 0 || k2 == 34) ? 1.0f : 2.0f;
        Wg[2 * e]     = alpha * cosf(a) / 68.0f;
        Wg[2 * e + 1] = alpha * sinf(a) / 68.0f;
    }
}

__global__ void k_zero(float* out, int n) {
    for (int i = blockIdx.x * 256 + threadIdx.x; i < n; i += gridDim.x * 256)
        out[i] = 0.0f;
}

// ---------- one-time kernel-spectrum transpose: K_t[bin][i][o][c] ----------
__global__ void k_ktrans(const float* __restrict__ kr, const float* __restrict__ ki,
                         float* __restrict__ Kt) {
    __shared__ float tr[64 * 37];   // [o][k2] pad 37 (stride%32=5 -> conflict-free)
    __shared__ float ti[64 * 37];
    int k1 = blockIdx.x >> 6, i = blockIdx.x & 63;
    int t = threadIdx.x;
    for (int e = t; e < 64 * KH; e += 256) {
        int o = e / KH, k2 = e % KH;
        size_t src = ((size_t)(o * 64 + i) * 68 + k1) * 68 + k2;
        tr[o * 37 + k2] = kr[src];
        ti[o * 37 + k2] = ki[src];
    }
    __syncthreads();
    for (int e = t; e < KH * 64; e += 256) {
        int k2 = e >> 6, o = e & 63;
        size_t dst = ((size_t)(k1 * KH + k2)) * 8192 + (size_t)i * 128 + o * 2;
        Kt[dst]     = tr[o * 37 + k2];
        Kt[dst + 1] = ti[o * 37 + k2];
    }
}

// ---------------- stage 1: row DFT ----------------
__global__ void k_fwd_row(const float* __restrict__ x, const float* __restrict__ Wf,
                          float* __restrict__ Y, int s) {
    __shared__ float xr[64 * 64];        // [c][i]
    __shared__ float wf[KH * 64 * 2];    // [k2][c]
    int nl = blockIdx.x >> 6, r = blockIdx.x & 63;
    int n = s + nl;
    int b = n >> 4, tr = (n >> 2) & 3, tc = n & 3;
    const float* src = x + (((size_t)(b * 256 + tr * 64 + r)) * 256 + tc * 64) * 64;
    int t = threadIdx.x;
    for (int e = t; e < 4096; e += 256) xr[e] = src[e];
    for (int e = t; e < KH * 64 * 2; e += 256) wf[e] = Wf[e];
    __syncthreads();
    int i = t & 63, kg = t >> 6;
    float* ybase = Y + (((size_t)nl * 64 + r) * 64 + i) * (2 * KH);
    for (int k2 = kg; k2 < KH; k2 += 4) {
        float ar = 0.f, ai = 0.f;
        const float* w = wf + k2 * 128;
        for (int c = 0; c < 64; ++c) {
            float v = xr[(c << 6) | i];
            ar += v * w[2 * c];
            ai += v * w[2 * c + 1];
        }
        ybase[2 * k2]     = ar;
        ybase[2 * k2 + 1] = ai;
    }
}

// ---------------- stage 2: column DFT ----------------
// X[bin][i][nl] = sum_r Wf[k1][r] * Y[nl][r][i][k2]
__global__ void k_fwd_col(const float* __restrict__ Y, const float* __restrict__ Wf,
                          float* __restrict__ X, int NT) {
    __shared__ float yl[64 * KH * 2];    // [r][k2c]
    __shared__ float wf[68 * 64 * 2];    // [k1][r]
    int nl = blockIdx.x >> 6, i = blockIdx.x & 63;
    int t = threadIdx.x;
    for (int e = t; e < 64 * KH * 2; e += 256) {
        int r = e / (2 * KH), rem = e % (2 * KH);
        yl[e] = Y[(((size_t)nl * 64 + r) * 64 + i) * (2 * KH) + rem];
    }
    for (int e = t; e < 68 * 64 * 2; e += 256) wf[e] = Wf[e];
    __syncthreads();
    for (int oi = t; oi < 68 * KH; oi += 256) {
        int k1 = oi / KH, k2 = oi % KH;
        float ar = 0.f, ai = 0.f;
        const float* w = wf + k1 * 128;
        const float* yy = yl + k2 * 2;
        for (int r = 0; r < 64; ++r) {
            float br = w[2 * r], bi = w[2 * r + 1];
            float cr = yy[r * 2 * KH], ci = yy[r * 2 * KH + 1];
            ar += br * cr - bi * ci;
            ai += br * ci + bi * cr;
        }
        size_t xi = ((size_t)oi * 64 + i) * NT + nl;
        X[2 * xi]     = ar;
        X[2 * xi + 1] = ai;
    }
}

// ---------------- stage 3: per-bin channel mix ----------------
// O[nl][k1][k2][o] = sum_i X[bin][i][nl] * K[bin][i][o]
__global__ void k_mix(const float* __restrict__ X, const float* __restrict__ Kt,
                      const float* __restrict__ kr, const float* __restrict__ ki,
                      float* __restrict__ O, int NT, int useKt) {
    __shared__ float xl[64 * NTMAX * 2];  // [i][n][c]
    __shared__ float kl[64 * 64 * 2];     // [i][o][c]
    int bin = blockIdx.x;
    int k1 = bin / KH, k2 = bin % KH;
    int t = threadIdx.x;
    for (int e = t; e < 64 * NT * 2; e += 256) xl[e] = X[(size_t)bin * 64 * NT * 2 + e];
    if (useKt) {
        const float* src = Kt + (size_t)bin * 8192;
        for (int e = t; e < 8192; e += 256) kl[e] = src[e];
    } else {
        for (int e = t; e < 4096; e += 256) {
            int o = e >> 6, i = e & 63;
            size_t gi = ((size_t)(o * 64 + i) * 68 + k1) * 68 + k2;
            kl[i * 128 + o * 2]     = kr[gi];
            kl[i * 128 + o * 2 + 1] = ki[gi];
        }
    }
    __syncthreads();
    int o = t & 63, g = t >> 6;
    for (int n = g; n < NT; n += 4) {
        float ar = 0.f, ai = 0.f;
        for (int i = 0; i < 64; ++i) {
            float br = kl[i * 128 + o * 2], bi = kl[i * 128 + o * 2 + 1];
            float cr = xl[(i * NT + n) * 2], ci = xl[(i * NT + n) * 2 + 1];
            ar += br * cr - bi * ci;
            ai += br * ci + bi * cr;
        }
        size_t oi = (((size_t)n * 68 + k1) * KH + k2) * 64 + o;
        O[2 * oi]     = ar;
        O[2 * oi + 1] = ai;
    }
}

// ---------------- stage 4: inverse column DFT ----------------
// Z[nl][k2][p][o] = sum_k1 Wi[p][k1] * O[nl][k1][k2][o]
__global__ void k_inv_col(const float* __restrict__ O, const float* __restrict__ Wi,
                          float* __restrict__ Z, int NT) {
    __shared__ float ol[68 * 128];       // [k1][o][c]  34 KB
    __shared__ float wi[68 * 68 * 2];    // [p][k1]     37 KB
    int nl = blockIdx.x / KH, k2 = blockIdx.x % KH;
    int t = threadIdx.x;
    const float* obase = O + ((size_t)nl * 68 * KH + k2) * 128;
    for (int e = t; e < 68 * 128; e += 256) {
        int k1 = e >> 7, oo = e & 127;
        ol[e] = obase[(size_t)k1 * KH * 128 + oo];
    }
    for (int e = t; e < 68 * 68 * 2; e += 256) wi[e] = Wi[e];
    __syncthreads();
    int o = t & 63, g = t >> 6;
    float* zbase = Z + (((size_t)nl * KH + k2) * 68) * 128;
    for (int p = g; p < 68; p += 4) {
        float ar = 0.f, ai = 0.f;
        const float* w = wi + p * 136;
        for (int k1 = 0; k1 < 68; ++k1) {
            float br = w[2 * k1], bi = w[2 * k1 + 1];
            float cr = ol[k1 * 128 + o * 2], ci = ol[k1 * 128 + o * 2 + 1];
            ar += br * cr - bi * ci;
            ai += br * ci + bi * cr;
        }
        zbase[(size_t)p * 128 + o * 2]     = ar;
        zbase[(size_t)p * 128 + o * 2 + 1] = ai;
    }
}

// ---------------- stage 5a: inverse row DFT ----------------
// S[nl][p][q][o] = sum_k2 Re( Z[nl][k2][p][o] * Wg[q][k2] )
__global__ void k_inv_row(const float* __restrict__ Z, const float* __restrict__ Wg,
                          float* __restrict__ S) {
    __shared__ float zl[KH * 128];       // [k2][o][c]  17.5 KB
    __shared__ float wgs[68 * 70];       // [q][k2c]    19 KB
    int nl = blockIdx.x / 68, p = blockIdx.x % 68;
    int t = threadIdx.x;
    const float* zsrc = Z + ((size_t)nl * KH * 68 + p) * 128;
    for (int e = t; e < KH * 128; e += 256) {
        int k2 = e >> 7, oo = e & 127;
        zl[e] = zsrc[(size_t)k2 * 68 * 128 + oo];
    }
    for (int e = t; e < 68 * 70; e += 256) wgs[e] = Wg[e];
    __syncthreads();
    int o = t & 63, g = t >> 6;
    float* sbase = S + ((size_t)nl * 68 + p) * 68 * 64 + o;
    for (int q = g; q < 68; q += 4) {
        const float* w = wgs + q * 70;
        float acc = 0.f;
        for (int k2 = 0; k2 < KH; ++k2) {
            acc = fmaf(zl[k2 * 128 + o * 2], w[2 * k2], acc);
            acc = fmaf(-zl[k2 * 128 + o * 2 + 1], w[2 * k2 + 1], acc);
        }
        sbase[(size_t)q * 64] = acc;
    }
}

// ---------------- stage 5b: overlap-add gather ----------------
__global__ void k_oadd(const float* __restrict__ S, const float* __restrict__ bias,
                       float* __restrict__ out, int s, int NT, int store_mode) {
    int y = blockIdx.x >> 2, xq = blockIdx.x & 3;
    int b = s >> 4;
    int t = threadIdx.x;
    int o = t & 63, xg = t >> 6;
    float bv = bias[o];
    int tr_hi = min(3, y / 66);
    int tr_lo = (y <= 67) ? 0 : (y - 2) / 66;
    for (int xx = 0; xx < 16; ++xx) {
        int x = xq * 64 + xg * 16 + xx;
        int tc_hi = min(3, x / 66);
        int tc_lo = (x <= 67) ? 0 : (x - 2) / 66;
        float acc = 0.f;
        for (int tr = tr_lo; tr <= tr_hi; ++tr) {
            int p = y - 66 * tr;
            for (int tc = tc_lo; tc <= tc_hi; ++tc) {
                int n = b * 16 + tr * 4 + tc;
                int nl = n - s;
                if (nl < 0 || nl >= NT) continue;
                int q = x - 66 * tc;
                acc += S[((((size_t)nl * 68 + p) * 68) + q) * 64 + o] + bv;
            }
        }
        size_t oidx = (((size_t)b * 256 + y) * 256 + x) * 64 + o;
        if (store_mode) out[oidx] = acc;
        else            out[oidx] += acc;
    }
}

extern "C" void kernel_launch(void* const* d_in, const int* in_sizes, int n_in,
                              void* d_out, int out_size, void* d_ws, size_t ws_size,
                              hipStream_t stream) {
    const float* x    = (const float*)d_in[0];
    const float* kr   = (const float*)d_in[1];
    const float* ki   = (const float*)d_in[2];
    const float* bias = (const float*)d_in[3];
    float* out = (float*)d_out;
    float* ws  = (float*)d_ws;

    // workspace ladder: prefer transposed kernel spectrum (K_t) + max NT
    int useKt = 1;
    int NT = 16;
    while (NT > 1 && (22720ull + KT_FLOATS + 3ull * (size_t)NT * 304640ull) * 4ull > ws_size)
        NT >>= 1;
    if ((22720ull + KT_FLOATS + 3ull * (size_t)NT * 304640ull) * 4ull > ws_size) {
        useKt = 0;
        NT = 16;
        while (NT > 1 && (22720ull + 3ull * (size_t)NT * 304640ull) * 4ull > ws_size)
            NT >>= 1;
    }

    float* Wf   = ws;                          // 8704 floats
    float* Wi   = ws + 8704;                   // 9248 floats
    float* Wg   = ws + 17952;                  // 4760 floats
    float* Kt   = ws + 22720;                  // KT_FLOATS (if useKt)
    float* bufA = Kt + (useKt ? KT_FLOATS : 0);
    float* bufB = bufA + (size_t)NT * 304640;  // X, then S
    float* bufC = bufB + (size_t)NT * 304640;  // O

    k_twiddle<<<1, 256, 0, stream>>>(ws);
    if (useKt)
        k_ktrans<<<68 * 64, 256, 0, stream>>>(kr, ki, Kt);
    int store_mode = (NT == 16) ? 1 : 0;
    if (!store_mode)
        k_zero<<<2048, 256, 0, stream>>>(out, 8 * 256 * 256 * 64);

    for (int s = 0; s < 128; s += NT) {
        k_fwd_row<<<NT * 64, 256, 0, stream>>>(x, Wf, bufA, s);
        k_fwd_col<<<NT * 64, 256, 0, stream>>>(bufA, Wf, bufB, NT);
        k_mix<<<68 * KH, 256, 0, stream>>>(bufB, Kt, kr, ki, bufC, NT, useKt);
        k_inv_col<<<NT * KH, 256, 0, stream>>>(bufC, Wi, bufA, NT);
        k_inv_row<<<NT * 68, 256, 0, stream>>>(bufA, Wg, bufB);
        k_oadd<<<256 * 4, 256, 0, stream>>>(bufB, bias, out, s, NT, store_mode);
    }
}

// Round 4
// 3296.454 us; speedup vs baseline: 1.6314x; 1.6314x over previous
//
#include <hip/hip_runtime.h>
#include <hip/hip_bf16.h>

// FFT-tiled conv: B=8, IMG=256, CIN=COUT=64, TILE=64, FFT=68, PAD=2.
// Frequency-domain per-tile conv via DFT-as-matmul, Hermitian half-spectrum
// (k2 in [0,35)), overlap-add gather. All fp32.
//
// Layouts (both producer-coalesced AND consumer-contiguous):
//   Y  [nl][r][i][k2c]
//   X  [bin][i][nl][c]            bin = k1*KH+k2
//   K_t[bin][i][o][c]             one-time transposed kernel spectrum (78 MB)
//   O  [nl][k2][k1][o][c]         mix writes 512B runs; inv_col reads contiguous
//   Z  [nl][p][k2][o][c]          inv_col writes 512B runs; inv_row reads contiguous
//   S  [nl][p][q][o]

#define FFTN 68
#define KH   35
#define NTMAX 16
#define KT_FLOATS (68ull * KH * 64 * 64 * 2)   // 19,496,960

__global__ void k_twiddle(float* ws) {
    const float TWO_PI = 6.28318530717958647692f;
    int t = threadIdx.x;
    float* Wf = ws;
    for (int e = t; e < 68 * 64; e += 256) {
        int k = e >> 6, m = e & 63;
        int ph = (k * (m + 2)) % 68;
        float a = TWO_PI * (float)ph / 68.0f;
        Wf[2 * e]     = cosf(a);
        Wf[2 * e + 1] = -sinf(a);
    }
    float* Wi = ws + 8704;
    for (int e = t; e < 68 * 68; e += 256) {
        int p = e / 68, k = e % 68;
        int ph = (p * k) % 68;
        float a = TWO_PI * (float)ph / 68.0f;
        Wi[2 * e]     = cosf(a) / 68.0f;
        Wi[2 * e + 1] = sinf(a) / 68.0f;
    }
    float* Wg = ws + 17952;
    for (int e = t; e < 68 * KH; e += 256) {
        int q = e / KH, k2 = e % KH;
        int ph = (q * k2) % 68;
        float a = TWO_PI * (float)ph / 68.0f;
        float alpha = (k2 == 0 || k2 == 34) ? 1.0f : 2.0f;
        Wg[2 * e]     = alpha * cosf(a) / 68.0f;
        Wg[2 * e + 1] = alpha * sinf(a) / 68.0f;
    }
}

__global__ void k_zero(float* out, int n) {
    for (int i = blockIdx.x * 256 + threadIdx.x; i < n; i += gridDim.x * 256)
        out[i] = 0.0f;
}

// ---------- one-time kernel-spectrum transpose: K_t[bin][i][o][c] ----------
__global__ void k_ktrans(const float* __restrict__ kr, const float* __restrict__ ki,
                         float* __restrict__ Kt) {
    __shared__ float tr[64 * 37];   // [o][k2] pad 37 -> conflict-free
    __shared__ float ti[64 * 37];
    int k1 = blockIdx.x >> 6, i = blockIdx.x & 63;
    int t = threadIdx.x;
    for (int e = t; e < 64 * KH; e += 256) {
        int o = e / KH, k2 = e % KH;
        size_t src = ((size_t)(o * 64 + i) * 68 + k1) * 68 + k2;
        tr[o * 37 + k2] = kr[src];
        ti[o * 37 + k2] = ki[src];
    }
    __syncthreads();
    for (int e = t; e < KH * 64; e += 256) {
        int k2 = e >> 6, o = e & 63;
        size_t dst = ((size_t)(k1 * KH + k2)) * 8192 + (size_t)i * 128 + o * 2;
        Kt[dst]     = tr[o * 37 + k2];
        Kt[dst + 1] = ti[o * 37 + k2];
    }
}

// ---------------- stage 1: row DFT ----------------
__global__ void k_fwd_row(const float* __restrict__ x, const float* __restrict__ Wf,
                          float* __restrict__ Y, int s) {
    __shared__ float xr[64 * 64];        // [c][i]
    __shared__ float wf[KH * 64 * 2];    // [k2][c]
    int nl = blockIdx.x >> 6, r = blockIdx.x & 63;
    int n = s + nl;
    int b = n >> 4, tr = (n >> 2) & 3, tc = n & 3;
    const float* src = x + (((size_t)(b * 256 + tr * 64 + r)) * 256 + tc * 64) * 64;
    int t = threadIdx.x;
    for (int e = t; e < 4096; e += 256) xr[e] = src[e];
    for (int e = t; e < KH * 64 * 2; e += 256) wf[e] = Wf[e];
    __syncthreads();
    int i = t & 63, kg = t >> 6;
    float* ybase = Y + (((size_t)nl * 64 + r) * 64 + i) * (2 * KH);
    for (int k2 = kg; k2 < KH; k2 += 4) {
        float ar = 0.f, ai = 0.f;
        const float* w = wf + k2 * 128;
        for (int c = 0; c < 64; ++c) {
            float v = xr[(c << 6) | i];
            ar += v * w[2 * c];
            ai += v * w[2 * c + 1];
        }
        ybase[2 * k2]     = ar;
        ybase[2 * k2 + 1] = ai;
    }
}

// ---------------- stage 2: column DFT ----------------
// X[bin][i][nl] = sum_r Wf[k1][r] * Y[nl][r][i][k2]
__global__ void k_fwd_col(const float* __restrict__ Y, const float* __restrict__ Wf,
                          float* __restrict__ X, int NT) {
    __shared__ float yl[64 * KH * 2];    // [r][k2c]
    __shared__ float wf[68 * 64 * 2];    // [k1][r]
    int nl = blockIdx.x >> 6, i = blockIdx.x & 63;
    int t = threadIdx.x;
    for (int e = t; e < 64 * KH * 2; e += 256) {
        int r = e / (2 * KH), rem = e % (2 * KH);
        yl[e] = Y[(((size_t)nl * 64 + r) * 64 + i) * (2 * KH) + rem];
    }
    for (int e = t; e < 68 * 64 * 2; e += 256) wf[e] = Wf[e];
    __syncthreads();
    for (int oi = t; oi < 68 * KH; oi += 256) {
        int k1 = oi / KH, k2 = oi % KH;
        float ar = 0.f, ai = 0.f;
        const float* w = wf + k1 * 128;
        const float* yy = yl + k2 * 2;
        for (int r = 0; r < 64; ++r) {
            float br = w[2 * r], bi = w[2 * r + 1];
            float cr = yy[r * 2 * KH], ci = yy[r * 2 * KH + 1];
            ar += br * cr - bi * ci;
            ai += br * ci + bi * cr;
        }
        size_t xi = ((size_t)oi * 64 + i) * NT + nl;
        X[2 * xi]     = ar;
        X[2 * xi + 1] = ai;
    }
}

// ---------------- stage 3: per-bin channel mix ----------------
// O[nl][k2][k1][o] = sum_i X[bin][i][nl] * K[bin][i][o]
__global__ void k_mix(const float* __restrict__ X, const float* __restrict__ Kt,
                      const float* __restrict__ kr, const float* __restrict__ ki,
                      float* __restrict__ O, int NT, int useKt) {
    __shared__ float xl[64 * NTMAX * 2];  // [i][n][c]
    __shared__ float kl[64 * 64 * 2];     // [i][o][c]
    int bin = blockIdx.x;
    int k1 = bin / KH, k2 = bin % KH;
    int t = threadIdx.x;
    for (int e = t; e < 64 * NT * 2; e += 256) xl[e] = X[(size_t)bin * 64 * NT * 2 + e];
    if (useKt) {
        const float* src = Kt + (size_t)bin * 8192;
        for (int e = t; e < 8192; e += 256) kl[e] = src[e];
    } else {
        for (int e = t; e < 4096; e += 256) {
            int o = e >> 6, i = e & 63;
            size_t gi = ((size_t)(o * 64 + i) * 68 + k1) * 68 + k2;
            kl[i * 128 + o * 2]     = kr[gi];
            kl[i * 128 + o * 2 + 1] = ki[gi];
        }
    }
    __syncthreads();
    int o = t & 63, g = t >> 6;
    for (int n = g; n < NT; n += 4) {
        float ar = 0.f, ai = 0.f;
        for (int i = 0; i < 64; ++i) {
            float br = kl[i * 128 + o * 2], bi = kl[i * 128 + o * 2 + 1];
            float cr = xl[(i * NT + n) * 2], ci = xl[(i * NT + n) * 2 + 1];
            ar += br * cr - bi * ci;
            ai += br * ci + bi * cr;
        }
        size_t oi = (((size_t)n * KH + k2) * 68 + k1) * 64 + o;
        O[2 * oi]     = ar;
        O[2 * oi + 1] = ai;
    }
}

// ---------------- stage 4: inverse column DFT ----------------
// Z[nl][p][k2][o] = sum_k1 Wi[p][k1] * O[nl][k2][k1][o]
__global__ __launch_bounds__(512) void k_inv_col(
        const float* __restrict__ O, const float* __restrict__ Wi,
        float* __restrict__ Z, int NT) {
    __shared__ float ol[68 * 128];       // [k1][o][c]  34 KB (only LDS user)
    int bid = blockIdx.x;
    int ph = bid & 1;                    // p half: [0,34) or [34,68)
    int rest = bid >> 1;
    int k2 = rest % KH, nl = rest / KH;
    int t = threadIdx.x;
    const float4* osrc = (const float4*)(O + ((size_t)nl * KH + k2) * 68 * 128);
    float4* ol4 = (float4*)ol;
    for (int e = t; e < 68 * 32; e += 512) ol4[e] = osrc[e];   // contiguous 34 KB
    __syncthreads();
    int o = t & 63, g = t >> 6;          // g in 0..7
    const float* oo_ = ol + o * 2;
    float* zbase = Z + (size_t)nl * 68 * KH * 128 + (size_t)k2 * 128 + o * 2;
    for (int j = 0; j < 5; ++j) {
        int pl = g + 8 * j;
        if (pl >= 34) break;
        int p = ph * 34 + pl;
        const float* w = Wi + p * 136;   // global broadcast, L1/L2-hot
        float ar = 0.f, ai = 0.f;
        #pragma unroll 17
        for (int k1 = 0; k1 < 68; k1 += 2) {
            float4 wv = *(const float4*)(w + 2 * k1);
            float2 c0 = *(const float2*)(oo_ + k1 * 128);
            float2 c1 = *(const float2*)(oo_ + k1 * 128 + 128);
            ar += wv.x * c0.x - wv.y * c0.y;
            ai += wv.x * c0.y + wv.y * c0.x;
            ar += wv.z * c1.x - wv.w * c1.y;
            ai += wv.z * c1.y + wv.w * c1.x;
        }
        *(float2*)(zbase + (size_t)p * KH * 128) = make_float2(ar, ai);
    }
}

// ---------------- stage 5a: inverse row DFT ----------------
// S[nl][p][q][o] = sum_k2 Re( Z[nl][p][k2][o] * Wg[q][k2] )
__global__ void k_inv_row(const float* __restrict__ Z, const float* __restrict__ Wg,
                          float* __restrict__ S) {
    __shared__ float zl[KH * 128];       // [k2][o][c]  17.5 KB
    __shared__ float wgs[68 * 70];       // [q][k2c]    19 KB
    int nl = blockIdx.x / 68, p = blockIdx.x % 68;
    int t = threadIdx.x;
    const float4* zsrc = (const float4*)(Z + ((size_t)(nl * 68 + p)) * KH * 128);
    float4* zl4 = (float4*)zl;
    for (int e = t; e < KH * 32; e += 256) zl4[e] = zsrc[e];   // contiguous 17.9 KB
    for (int e = t; e < 68 * 70; e += 256) wgs[e] = Wg[e];
    __syncthreads();
    int o = t & 63, g = t >> 6;
    float* sbase = S + ((size_t)nl * 68 + p) * 68 * 64 + o;
    for (int q = g; q < 68; q += 4) {
        const float* w = wgs + q * 70;
        float acc = 0.f;
        for (int k2 = 0; k2 < KH; ++k2) {
            acc = fmaf(zl[k2 * 128 + o * 2], w[2 * k2], acc);
            acc = fmaf(-zl[k2 * 128 + o * 2 + 1], w[2 * k2 + 1], acc);
        }
        sbase[(size_t)q * 64] = acc;
    }
}

// ---------------- stage 5b: overlap-add gather ----------------
__global__ void k_oadd(const float* __restrict__ S, const float* __restrict__ bias,
                       float* __restrict__ out, int s, int NT, int store_mode) {
    int y = blockIdx.x >> 2, xq = blockIdx.x & 3;
    int b = s >> 4;
    int t = threadIdx.x;
    int o = t & 63, xg = t >> 6;
    float bv = bias[o];
    int tr_hi = min(3, y / 66);
    int tr_lo = (y <= 67) ? 0 : (y - 2) / 66;
    for (int xx = 0; xx < 16; ++xx) {
        int x = xq * 64 + xg * 16 + xx;
        int tc_hi = min(3, x / 66);
        int tc_lo = (x <= 67) ? 0 : (x - 2) / 66;
        float acc = 0.f;
        for (int tr = tr_lo; tr <= tr_hi; ++tr) {
            int p = y - 66 * tr;
            for (int tc = tc_lo; tc <= tc_hi; ++tc) {
                int n = b * 16 + tr * 4 + tc;
                int nl = n - s;
                if (nl < 0 || nl >= NT) continue;
                int q = x - 66 * tc;
                acc += S[((((size_t)nl * 68 + p) * 68) + q) * 64 + o] + bv;
            }
        }
        size_t oidx = (((size_t)b * 256 + y) * 256 + x) * 64 + o;
        if (store_mode) out[oidx] = acc;
        else            out[oidx] += acc;
    }
}

extern "C" void kernel_launch(void* const* d_in, const int* in_sizes, int n_in,
                              void* d_out, int out_size, void* d_ws, size_t ws_size,
                              hipStream_t stream) {
    const float* x    = (const float*)d_in[0];
    const float* kr   = (const float*)d_in[1];
    const float* ki   = (const float*)d_in[2];
    const float* bias = (const float*)d_in[3];
    float* out = (float*)d_out;
    float* ws  = (float*)d_ws;

    int useKt = 1;
    int NT = 16;
    while (NT > 1 && (22720ull + KT_FLOATS + 3ull * (size_t)NT * 304640ull) * 4ull > ws_size)
        NT >>= 1;
    if ((22720ull + KT_FLOATS + 3ull * (size_t)NT * 304640ull) * 4ull > ws_size) {
        useKt = 0;
        NT = 16;
        while (NT > 1 && (22720ull + 3ull * (size_t)NT * 304640ull) * 4ull > ws_size)
            NT >>= 1;
    }

    float* Wf   = ws;                          // 8704 floats
    float* Wi   = ws + 8704;                   // 9248 floats
    float* Wg   = ws + 17952;                  // 4760 floats
    float* Kt   = ws + 22720;                  // KT_FLOATS (if useKt)
    float* bufA = Kt + (useKt ? KT_FLOATS : 0);
    float* bufB = bufA + (size_t)NT * 304640;  // X, then S
    float* bufC = bufB + (size_t)NT * 304640;  // O

    k_twiddle<<<1, 256, 0, stream>>>(ws);
    if (useKt)
        k_ktrans<<<68 * 64, 256, 0, stream>>>(kr, ki, Kt);
    int store_mode = (NT == 16) ? 1 : 0;
    if (!store_mode)
        k_zero<<<2048, 256, 0, stream>>>(out, 8 * 256 * 256 * 64);

    for (int s = 0; s < 128; s += NT) {
        k_fwd_row<<<NT * 64, 256, 0, stream>>>(x, Wf, bufA, s);
        k_fwd_col<<<NT * 64, 256, 0, stream>>>(bufA, Wf, bufB, NT);
        k_mix<<<68 * KH, 256, 0, stream>>>(bufB, Kt, kr, ki, bufC, NT, useKt);
        k_inv_col<<<NT * KH * 2, 512, 0, stream>>>(bufC, Wi, bufA, NT);
        k_inv_row<<<NT * 68, 256, 0, stream>>>(bufA, Wg, bufB);
        k_oadd<<<256 * 4, 256, 0, stream>>>(bufB, bias, out, s, NT, store_mode);
    }
}

// Round 5
// 1883.782 us; speedup vs baseline: 2.8549x; 1.7499x over previous
//
#include <hip/hip_runtime.h>
#include <hip/hip_bf16.h>

// FFT-tiled conv: B=8, IMG=256, CIN=COUT=64, TILE=64, FFT=68, PAD=2.
// Frequency-domain per-tile conv via DFT-as-matmul, Hermitian half-spectrum
// (k2 in [0,35)), fused inverse-row-DFT + overlap-add. All fp32.
//
// Layouts:
//   Y  [nl][r][i][k2c]
//   X  [bin][i][nl][c]            bin = k1*KH+k2
//   K_t[bin][i][o][c]             one-time transposed kernel spectrum (78 MB)
//   O  [nl][k2][k1][o][c]
//   Z  [nl][p][k2][o][c]
//   (S eliminated: stage5 fused)

#define FFTN 68
#define KH   35
#define NTMAX 16
#define KT_FLOATS (68ull * KH * 64 * 64 * 2)   // 19,496,960

__global__ void k_twiddle(float* ws) {
    const float TWO_PI = 6.28318530717958647692f;
    int t = threadIdx.x;
    float* Wf = ws;
    for (int e = t; e < 68 * 64; e += 256) {
        int k = e >> 6, m = e & 63;
        int ph = (k * (m + 2)) % 68;
        float a = TWO_PI * (float)ph / 68.0f;
        Wf[2 * e]     = cosf(a);
        Wf[2 * e + 1] = -sinf(a);
    }
    float* Wi = ws + 8704;
    for (int e = t; e < 68 * 68; e += 256) {
        int p = e / 68, k = e % 68;
        int ph = (p * k) % 68;
        float a = TWO_PI * (float)ph / 68.0f;
        Wi[2 * e]     = cosf(a) / 68.0f;
        Wi[2 * e + 1] = sinf(a) / 68.0f;
    }
    float* Wg = ws + 17952;
    for (int e = t; e < 68 * KH; e += 256) {
        int q = e / KH, k2 = e % KH;
        int ph = (q * k2) % 68;
        float a = TWO_PI * (float)ph / 68.0f;
        float alpha = (k2 == 0 || k2 == 34) ? 1.0f : 2.0f;
        Wg[2 * e]     = alpha * cosf(a) / 68.0f;
        Wg[2 * e + 1] = alpha * sinf(a) / 68.0f;
    }
}

__global__ void k_zero(float* out, int n) {
    for (int i = blockIdx.x * 256 + threadIdx.x; i < n; i += gridDim.x * 256)
        out[i] = 0.0f;
}

// ---------- one-time kernel-spectrum transpose: K_t[bin][i][o][c] ----------
__global__ void k_ktrans(const float* __restrict__ kr, const float* __restrict__ ki,
                         float* __restrict__ Kt) {
    __shared__ float tr[64 * 37];
    __shared__ float ti[64 * 37];
    int k1 = blockIdx.x >> 6, i = blockIdx.x & 63;
    int t = threadIdx.x;
    for (int e = t; e < 64 * KH; e += 256) {
        int o = e / KH, k2 = e % KH;
        size_t src = ((size_t)(o * 64 + i) * 68 + k1) * 68 + k2;
        tr[o * 37 + k2] = kr[src];
        ti[o * 37 + k2] = ki[src];
    }
    __syncthreads();
    for (int e = t; e < KH * 64; e += 256) {
        int k2 = e >> 6, o = e & 63;
        size_t dst = ((size_t)(k1 * KH + k2)) * 8192 + (size_t)i * 128 + o * 2;
        Kt[dst]     = tr[o * 37 + k2];
        Kt[dst + 1] = ti[o * 37 + k2];
    }
}

// ---------------- stage 1: row DFT (LDS-buffered coalesced output) ----------
__global__ void k_fwd_row(const float* __restrict__ x, const float* __restrict__ Wf,
                          float* __restrict__ Y, int s) {
    __shared__ float xr[64 * 64];        // [c][i]    16 KB
    __shared__ float wf[KH * 64 * 2];    // [k2][c]   17.9 KB
    __shared__ float yout[64 * 70];      // [i][k2c]  17.9 KB
    int nl = blockIdx.x >> 6, r = blockIdx.x & 63;
    int n = s + nl;
    int b = n >> 4, tr = (n >> 2) & 3, tc = n & 3;
    const float* src = x + (((size_t)(b * 256 + tr * 64 + r)) * 256 + tc * 64) * 64;
    int t = threadIdx.x;
    const float4* src4 = (const float4*)src;
    float4* xr4 = (float4*)xr;
    for (int e = t; e < 1024; e += 256) xr4[e] = src4[e];
    for (int e = t; e < KH * 64 * 2; e += 256) wf[e] = Wf[e];
    __syncthreads();
    int i = t & 63, kg = t >> 6;
    for (int k2 = kg; k2 < KH; k2 += 4) {
        float ar = 0.f, ai = 0.f;
        const float* w = wf + k2 * 128;
        for (int c = 0; c < 64; ++c) {
            float v = xr[(c << 6) | i];
            ar += v * w[2 * c];
            ai += v * w[2 * c + 1];
        }
        yout[i * 70 + 2 * k2]     = ar;
        yout[i * 70 + 2 * k2 + 1] = ai;
    }
    __syncthreads();
    float4* ydst = (float4*)(Y + ((size_t)(nl * 64 + r)) * 4480);
    const float4* ysrc = (const float4*)yout;
    for (int e = t; e < 1120; e += 256) ydst[e] = ysrc[e];
}

// ---------------- stage 2: column DFT ----------------
// X[bin][i][nl] = sum_r Wf[k1][r] * Y[nl][r][i][k2]
__global__ void k_fwd_col(const float* __restrict__ Y, const float* __restrict__ Wf,
                          float* __restrict__ X, int NT) {
    __shared__ float yl[64 * KH * 2];    // [r][k2c]
    __shared__ float wf[68 * 64 * 2];    // [k1][r]
    int nl = blockIdx.x >> 6, i = blockIdx.x & 63;
    int t = threadIdx.x;
    for (int e = t; e < 64 * KH * 2; e += 256) {
        int r = e / (2 * KH), rem = e % (2 * KH);
        yl[e] = Y[(((size_t)nl * 64 + r) * 64 + i) * (2 * KH) + rem];
    }
    for (int e = t; e < 68 * 64 * 2; e += 256) wf[e] = Wf[e];
    __syncthreads();
    for (int oi = t; oi < 68 * KH; oi += 256) {
        int k1 = oi / KH, k2 = oi % KH;
        float ar = 0.f, ai = 0.f;
        const float* w = wf + k1 * 128;
        const float* yy = yl + k2 * 2;
        for (int r = 0; r < 64; ++r) {
            float br = w[2 * r], bi = w[2 * r + 1];
            float cr = yy[r * 2 * KH], ci = yy[r * 2 * KH + 1];
            ar += br * cr - bi * ci;
            ai += br * ci + bi * cr;
        }
        size_t xi = ((size_t)oi * 64 + i) * NT + nl;
        X[2 * xi]     = ar;
        X[2 * xi + 1] = ai;
    }
}

// ---------------- stage 3: per-bin channel mix ----------------
// O[nl][k2][k1][o] = sum_i X[bin][i][nl] * K[bin][i][o]
__global__ void k_mix(const float* __restrict__ X, const float* __restrict__ Kt,
                      const float* __restrict__ kr, const float* __restrict__ ki,
                      float* __restrict__ O, int NT, int useKt) {
    __shared__ float xl[64 * NTMAX * 2];  // [i][n][c]
    __shared__ float kl[64 * 64 * 2];     // [i][o][c]
    int bin = blockIdx.x;
    int k1 = bin / KH, k2 = bin % KH;
    int t = threadIdx.x;
    for (int e = t; e < 64 * NT * 2; e += 256) xl[e] = X[(size_t)bin * 64 * NT * 2 + e];
    if (useKt) {
        const float* src = Kt + (size_t)bin * 8192;
        for (int e = t; e < 8192; e += 256) kl[e] = src[e];
    } else {
        for (int e = t; e < 4096; e += 256) {
            int o = e >> 6, i = e & 63;
            size_t gi = ((size_t)(o * 64 + i) * 68 + k1) * 68 + k2;
            kl[i * 128 + o * 2]     = kr[gi];
            kl[i * 128 + o * 2 + 1] = ki[gi];
        }
    }
    __syncthreads();
    int o = t & 63, g = t >> 6;
    for (int n = g; n < NT; n += 4) {
        float ar = 0.f, ai = 0.f;
        for (int i = 0; i < 64; ++i) {
            float br = kl[i * 128 + o * 2], bi = kl[i * 128 + o * 2 + 1];
            float cr = xl[(i * NT + n) * 2], ci = xl[(i * NT + n) * 2 + 1];
            ar += br * cr - bi * ci;
            ai += br * ci + bi * cr;
        }
        size_t oi = (((size_t)n * KH + k2) * 68 + k1) * 64 + o;
        O[2 * oi]     = ar;
        O[2 * oi + 1] = ai;
    }
}

// ---------------- stage 4: inverse column DFT ----------------
// Z[nl][p][k2][o] = sum_k1 Wi[p][k1] * O[nl][k2][k1][o]
__global__ __launch_bounds__(512) void k_inv_col(
        const float* __restrict__ O, const float* __restrict__ Wi,
        float* __restrict__ Z, int NT) {
    __shared__ float ol[68 * 128];       // [k1][o][c]  34 KB
    int bid = blockIdx.x;
    int ph = bid & 1;
    int rest = bid >> 1;
    int k2 = rest % KH, nl = rest / KH;
    int t = threadIdx.x;
    const float4* osrc = (const float4*)(O + ((size_t)nl * KH + k2) * 68 * 128);
    float4* ol4 = (float4*)ol;
    for (int e = t; e < 68 * 32; e += 512) ol4[e] = osrc[e];
    __syncthreads();
    int o = t & 63, g = t >> 6;
    const float* oo_ = ol + o * 2;
    float* zbase = Z + (size_t)nl * 68 * KH * 128 + (size_t)k2 * 128 + o * 2;
    for (int j = 0; j < 5; ++j) {
        int pl = g + 8 * j;
        if (pl >= 34) break;
        int p = ph * 34 + pl;
        const float* w = Wi + p * 136;
        float ar = 0.f, ai = 0.f;
        #pragma unroll 17
        for (int k1 = 0; k1 < 68; k1 += 2) {
            float4 wv = *(const float4*)(w + 2 * k1);
            float2 c0 = *(const float2*)(oo_ + k1 * 128);
            float2 c1 = *(const float2*)(oo_ + k1 * 128 + 128);
            ar += wv.x * c0.x - wv.y * c0.y;
            ai += wv.x * c0.y + wv.y * c0.x;
            ar += wv.z * c1.x - wv.w * c1.y;
            ai += wv.z * c1.y + wv.w * c1.x;
        }
        *(float2*)(zbase + (size_t)p * KH * 128) = make_float2(ar, ai);
    }
}

// ---------------- stage 5 (fused): inverse row DFT + overlap-add ------------
// out[b,y,x,o] = sum_{contrib (tr,tc)} [ bias[o] +
//     sum_k2 Re( Z[nl][p][k2][o] * Wg[q][k2] ) ],  p=y-66tr, q=x-66tc
// block = (y, x-half); 1024 threads = 32 x-lanes x 32 o-pairs.
// Requires NT==16 (whole image in chunk).
__global__ __launch_bounds__(1024) void k_fused_inv(
        const float* __restrict__ Z, const float* __restrict__ Wg,
        const float* __restrict__ bias, float* __restrict__ out, int s) {
    __shared__ float zs[6 * 4480];       // up to 6 slices  107.5 KB
    __shared__ float wg[68 * 70];        // 19 KB
    int y  = blockIdx.x >> 1;
    int xh = blockIdx.x & 1;
    int x0 = xh << 7;
    int b  = s >> 4;
    int t  = threadIdx.x;

    int tr_hi = min(3, y / 66);
    int tr_lo = (y <= 67) ? 0 : (y - 2) / 66;
    int tcs = (x0 <= 67) ? 0 : (x0 - 2) / 66;
    int tce = min(3, (x0 + 127) / 66);
    int ntr = tr_hi - tr_lo + 1;
    int ntc = tce - tcs + 1;

    // stage Z slices (contiguous float4 per slice)
    int total4 = ntr * ntc * 1120;
    float4* zs4 = (float4*)zs;
    for (int e = t; e < total4; e += 1024) {
        int sl = e / 1120, rem = e % 1120;
        int tr = tr_lo + sl / ntc, tc = tcs + sl % ntc;
        int nl = tr * 4 + tc;
        int p  = y - 66 * tr;
        const float4* src = (const float4*)(Z + ((size_t)(nl * 68 + p)) * 4480);
        zs4[e] = src[rem];
    }
    for (int e = t; e < 68 * 70; e += 1024) wg[e] = Wg[e];
    __syncthreads();

    int op = t & 31;                     // o-pair: o = 2*op, 2*op+1
    int xr = t >> 5;                     // 0..31
    float bv0 = bias[2 * op], bv1 = bias[2 * op + 1];

    for (int j = 0; j < 4; ++j) {
        int x = x0 + j * 32 + xr;
        float acc0 = 0.f, acc1 = 0.f;
        int cnt = 0;
        for (int tr = tr_lo; tr <= tr_hi; ++tr) {
            for (int tc = tcs; tc <= tce; ++tc) {
                int q = x - 66 * tc;
                if (q < 0 || q >= 68) continue;
                const float* zb = zs + ((tr - tr_lo) * ntc + (tc - tcs)) * 4480 + op * 4;
                const float* wr = wg + q * 70;
                #pragma unroll 7
                for (int k2 = 0; k2 < KH; ++k2) {
                    float4 zv = *(const float4*)(zb + k2 * 128);
                    float2 wv = *(const float2*)(wr + 2 * k2);
                    acc0 += zv.x * wv.x - zv.y * wv.y;
                    acc1 += zv.z * wv.x - zv.w * wv.y;
                }
                ++cnt;
            }
        }
        float2 res = make_float2(acc0 + cnt * bv0, acc1 + cnt * bv1);
        *(float2*)(out + (((size_t)(b * 256 + y)) * 256 + x) * 64 + op * 2) = res;
    }
}

// ---------------- fallback stage 5 (NT<16): separate inv_row + oadd ---------
__global__ void k_inv_row(const float* __restrict__ Z, const float* __restrict__ Wg,
                          float* __restrict__ S) {
    __shared__ float zl[KH * 128];
    __shared__ float wgs[68 * 70];
    int nl = blockIdx.x / 68, p = blockIdx.x % 68;
    int t = threadIdx.x;
    const float4* zsrc = (const float4*)(Z + ((size_t)(nl * 68 + p)) * KH * 128);
    float4* zl4 = (float4*)zl;
    for (int e = t; e < KH * 32; e += 256) zl4[e] = zsrc[e];
    for (int e = t; e < 68 * 70; e += 256) wgs[e] = Wg[e];
    __syncthreads();
    int o = t & 63, g = t >> 6;
    float* sbase = S + ((size_t)nl * 68 + p) * 68 * 64 + o;
    for (int q = g; q < 68; q += 4) {
        const float* w = wgs + q * 70;
        float acc = 0.f;
        for (int k2 = 0; k2 < KH; ++k2) {
            acc = fmaf(zl[k2 * 128 + o * 2], w[2 * k2], acc);
            acc = fmaf(-zl[k2 * 128 + o * 2 + 1], w[2 * k2 + 1], acc);
        }
        sbase[(size_t)q * 64] = acc;
    }
}

__global__ void k_oadd(const float* __restrict__ S, const float* __restrict__ bias,
                       float* __restrict__ out, int s, int NT) {
    int y = blockIdx.x >> 2, xq = blockIdx.x & 3;
    int b = s >> 4;
    int t = threadIdx.x;
    int o = t & 63, xg = t >> 6;
    float bv = bias[o];
    int tr_hi = min(3, y / 66);
    int tr_lo = (y <= 67) ? 0 : (y - 2) / 66;
    for (int xx = 0; xx < 16; ++xx) {
        int x = xq * 64 + xg * 16 + xx;
        int tc_hi = min(3, x / 66);
        int tc_lo = (x <= 67) ? 0 : (x - 2) / 66;
        float acc = 0.f;
        for (int tr = tr_lo; tr <= tr_hi; ++tr) {
            int p = y - 66 * tr;
            for (int tc = tc_lo; tc <= tc_hi; ++tc) {
                int n = b * 16 + tr * 4 + tc;
                int nl = n - s;
                if (nl < 0 || nl >= NT) continue;
                int q = x - 66 * tc;
                acc += S[((((size_t)nl * 68 + p) * 68) + q) * 64 + o] + bv;
            }
        }
        size_t oidx = (((size_t)b * 256 + y) * 256 + x) * 64 + o;
        out[oidx] += acc;
    }
}

extern "C" void kernel_launch(void* const* d_in, const int* in_sizes, int n_in,
                              void* d_out, int out_size, void* d_ws, size_t ws_size,
                              hipStream_t stream) {
    const float* x    = (const float*)d_in[0];
    const float* kr   = (const float*)d_in[1];
    const float* ki   = (const float*)d_in[2];
    const float* bias = (const float*)d_in[3];
    float* out = (float*)d_out;
    float* ws  = (float*)d_ws;

    int useKt = 1;
    int NT = 16;
    while (NT > 1 && (22720ull + KT_FLOATS + 3ull * (size_t)NT * 304640ull) * 4ull > ws_size)
        NT >>= 1;
    if ((22720ull + KT_FLOATS + 3ull * (size_t)NT * 304640ull) * 4ull > ws_size) {
        useKt = 0;
        NT = 16;
        while (NT > 1 && (22720ull + 3ull * (size_t)NT * 304640ull) * 4ull > ws_size)
            NT >>= 1;
    }

    float* Wf   = ws;
    float* Wi   = ws + 8704;
    float* Wg   = ws + 17952;
    float* Kt   = ws + 22720;
    float* bufA = Kt + (useKt ? KT_FLOATS : 0);
    float* bufB = bufA + (size_t)NT * 304640;  // X (and S in fallback)
    float* bufC = bufB + (size_t)NT * 304640;  // O

    k_twiddle<<<1, 256, 0, stream>>>(ws);
    if (useKt)
        k_ktrans<<<68 * 64, 256, 0, stream>>>(kr, ki, Kt);
    if (NT != 16)
        k_zero<<<2048, 256, 0, stream>>>(out, 8 * 256 * 256 * 64);

    for (int s = 0; s < 128; s += NT) {
        k_fwd_row<<<NT * 64, 256, 0, stream>>>(x, Wf, bufA, s);
        k_fwd_col<<<NT * 64, 256, 0, stream>>>(bufA, Wf, bufB, NT);
        k_mix<<<68 * KH, 256, 0, stream>>>(bufB, Kt, kr, ki, bufC, NT, useKt);
        k_inv_col<<<NT * KH * 2, 512, 0, stream>>>(bufC, Wi, bufA, NT);
        if (NT == 16) {
            k_fused_inv<<<512, 1024, 0, stream>>>(bufA, Wg, bias, out, s);
        } else {
            k_inv_row<<<NT * 68, 256, 0, stream>>>(bufA, Wg, bufB);
            k_oadd<<<256 * 4, 256, 0, stream>>>(bufB, bias, out, s, NT);
        }
    }
}

// Round 6
// 1502.765 us; speedup vs baseline: 3.5787x; 1.2535x over previous
//
#include <hip/hip_runtime.h>
#include <hip/hip_bf16.h>

// FFT-tiled conv: B=8, IMG=256, CIN=COUT=64, TILE=64, FFT=68, PAD=2.
// Frequency-domain per-tile conv via DFT-as-matmul, Hermitian half-spectrum
// (k2 in [0,35)), fused inverse-row-DFT + overlap-add. All fp32.
// Single-pass: one launch per stage, all 128 tiles, 2-buffer aliasing.
//
// Layouts (per 16-tile chunk slot of CHS floats):
//   Y  [nl][r][i][k2c]        in bufA     (nl*64+r)*4480
//   X  [bin][i][nl][c]        in bufB     bin*2048 + i*32 + nl*2
//   K_t[bin][i][o][c]         78 MB, one-time
//   O  [nl][k2][k1][o][c]     in bufA     ((nl*35+k2)*68+k1)*128
//   Z  [nl][p][k2][o][c]      in bufB     ((nl*68+p)*35+k2)*128

#define KH   35
#define CHS  4874240ull                       // floats per chunk slot
#define KT_FLOATS (68ull * KH * 64 * 64 * 2)  // 19,496,960

__global__ void k_twiddle(float* ws) {
    const float TWO_PI = 6.28318530717958647692f;
    int t = threadIdx.x;
    float* Wf = ws;
    for (int e = t; e < 68 * 64; e += 256) {
        int k = e >> 6, m = e & 63;
        int ph = (k * (m + 2)) % 68;
        float a = TWO_PI * (float)ph / 68.0f;
        Wf[2 * e]     = cosf(a);
        Wf[2 * e + 1] = -sinf(a);
    }
    float* Wi = ws + 8704;
    for (int e = t; e < 68 * 68; e += 256) {
        int p = e / 68, k = e % 68;
        int ph = (p * k) % 68;
        float a = TWO_PI * (float)ph / 68.0f;
        Wi[2 * e]     = cosf(a) / 68.0f;
        Wi[2 * e + 1] = sinf(a) / 68.0f;
    }
    float* Wg = ws + 17952;
    for (int e = t; e < 68 * KH; e += 256) {
        int q = e / KH, k2 = e % KH;
        int ph = (q * k2) % 68;
        float a = TWO_PI * (float)ph / 68.0f;
        float alpha = (k2 == 0 || k2 == 34) ? 1.0f : 2.0f;
        Wg[2 * e]     = alpha * cosf(a) / 68.0f;
        Wg[2 * e + 1] = alpha * sinf(a) / 68.0f;
    }
}

// ---------- one-time kernel-spectrum transpose: K_t[bin][i][o][c] ----------
__global__ void k_ktrans(const float* __restrict__ kr, const float* __restrict__ ki,
                         float* __restrict__ Kt) {
    __shared__ float tr[64 * 37];
    __shared__ float ti[64 * 37];
    int k1 = blockIdx.x >> 6, i = blockIdx.x & 63;
    int t = threadIdx.x;
    for (int e = t; e < 64 * KH; e += 256) {
        int o = e / KH, k2 = e % KH;
        size_t src = ((size_t)(o * 64 + i) * 68 + k1) * 68 + k2;
        tr[o * 37 + k2] = kr[src];
        ti[o * 37 + k2] = ki[src];
    }
    __syncthreads();
    for (int e = t; e < KH * 64; e += 256) {
        int k2 = e >> 6, o = e & 63;
        size_t dst = ((size_t)(k1 * KH + k2)) * 8192 + (size_t)i * 128 + o * 2;
        Kt[dst]     = tr[o * 37 + k2];
        Kt[dst + 1] = ti[o * 37 + k2];
    }
}

// ---------------- stage 1: row DFT ----------------
__global__ void k_fwd_row(const float* __restrict__ x, const float* __restrict__ Wf,
                          float* __restrict__ Y, int c0) {
    __shared__ float xr[64 * 64];
    __shared__ float wf[KH * 64 * 2];
    __shared__ float yout[64 * 70];
    int lc = blockIdx.x >> 10;
    int rem = blockIdx.x & 1023;
    int nl = rem >> 6, r = rem & 63;
    int n = (c0 + lc) * 16 + nl;
    int b = n >> 4, tr = (n >> 2) & 3, tc = n & 3;
    const float* src = x + (((size_t)(b * 256 + tr * 64 + r)) * 256 + tc * 64) * 64;
    int t = threadIdx.x;
    const float4* src4 = (const float4*)src;
    float4* xr4 = (float4*)xr;
    for (int e = t; e < 1024; e += 256) xr4[e] = src4[e];
    for (int e = t; e < KH * 64 * 2; e += 256) wf[e] = Wf[e];
    __syncthreads();
    int i = t & 63, kg = t >> 6;
    for (int k2 = kg; k2 < KH; k2 += 4) {
        float ar = 0.f, ai = 0.f;
        const float* w = wf + k2 * 128;
        for (int c = 0; c < 64; ++c) {
            float v = xr[(c << 6) | i];
            ar += v * w[2 * c];
            ai += v * w[2 * c + 1];
        }
        yout[i * 70 + 2 * k2]     = ar;
        yout[i * 70 + 2 * k2 + 1] = ai;
    }
    __syncthreads();
    float4* ydst = (float4*)(Y + (size_t)lc * CHS + ((size_t)(nl * 64 + r)) * 4480);
    const float4* ysrc = (const float4*)yout;
    for (int e = t; e < 1120; e += 256) ydst[e] = ysrc[e];
}

// ---------------- stage 2: column DFT (i-pair blocked) ----------------
// X[bin][i][nl] = sum_r Wf[k1][r] * Y[nl][r][i][k2]
__global__ void k_fwd_col(const float* __restrict__ Y, const float* __restrict__ Wf,
                          float* __restrict__ X) {
    __shared__ float yl[2 * 64 * 70];    // 35.8 KB: [is][r][k2c]
    __shared__ float wf[68 * 64 * 2];    // 34.8 KB: [k1][r]
    int lc = blockIdx.x >> 9;
    int rem = blockIdx.x & 511;
    int ip = rem >> 4;                   // i-pair 0..31
    int nl = rem & 15;
    const float* Yc = Y + (size_t)lc * CHS;
    float* Xc = X + (size_t)lc * CHS;
    int t = threadIdx.x;
    for (int e = t; e < 2 * 64 * 70; e += 256) {
        int is = e / 4480, rr = e % 4480;
        int r = rr / 70, k2c = rr % 70;
        yl[e] = Yc[((size_t)(nl * 64 + r)) * 4480 + (size_t)(2 * ip + is) * 70 + k2c];
    }
    for (int e = t; e < 68 * 64 * 2; e += 256) wf[e] = Wf[e];
    __syncthreads();
    for (int oi = t; oi < 68 * KH; oi += 256) {
        int k1 = oi / KH, k2 = oi % KH;
        const float* w  = wf + k1 * 128;
        const float* y0 = yl + k2 * 2;
        const float* y1 = yl + 4480 + k2 * 2;
        float a0r = 0.f, a0i = 0.f, a1r = 0.f, a1i = 0.f;
        for (int r = 0; r < 64; ++r) {
            float2 wv = *(const float2*)(w + 2 * r);
            float2 c0 = *(const float2*)(y0 + r * 70);
            float2 c1 = *(const float2*)(y1 + r * 70);
            a0r += wv.x * c0.x - wv.y * c0.y;
            a0i += wv.x * c0.y + wv.y * c0.x;
            a1r += wv.x * c1.x - wv.y * c1.y;
            a1i += wv.x * c1.y + wv.y * c1.x;
        }
        size_t xi0 = ((size_t)oi * 64 + 2 * ip) * 16 + nl;
        *(float2*)(Xc + 2 * xi0)        = make_float2(a0r, a0i);
        *(float2*)(Xc + 2 * (xi0 + 16)) = make_float2(a1r, a1i);
    }
}

// ---------------- stage 3: per-bin channel mix (2o x 2n register tile) -----
// O[nl][k2][k1][o] = sum_i X[bin][i][nl] * K[bin][i][o]
__global__ void k_mix(const float* __restrict__ X, const float* __restrict__ Kt,
                      const float* __restrict__ kr, const float* __restrict__ ki,
                      float* __restrict__ O, int useKt) {
    __shared__ float xl[64 * 16 * 2];    // [i][n][c]  8 KB
    __shared__ float kl[64 * 64 * 2];    // [i][o][c] 32 KB
    int lc = blockIdx.x / 2380;
    int bin = blockIdx.x % 2380;
    int k1 = bin / KH, k2 = bin % KH;
    const float* Xc = X + (size_t)lc * CHS;
    float* Oc = O + (size_t)lc * CHS;
    int t = threadIdx.x;
    for (int e = t; e < 2048; e += 256) xl[e] = Xc[(size_t)bin * 2048 + e];
    if (useKt) {
        const float* src = Kt + (size_t)bin * 8192;
        for (int e = t; e < 8192; e += 256) kl[e] = src[e];
    } else {
        for (int e = t; e < 4096; e += 256) {
            int o = e >> 6, i = e & 63;
            size_t gi = ((size_t)(o * 64 + i) * 68 + k1) * 68 + k2;
            kl[i * 128 + o * 2]     = kr[gi];
            kl[i * 128 + o * 2 + 1] = ki[gi];
        }
    }
    __syncthreads();
    int op = t & 31, g = t >> 5;         // o = 2op,2op+1 ; n = g, g+8
    float a0r=0,a0i=0,a1r=0,a1i=0,b0r=0,b0i=0,b1r=0,b1i=0;
    for (int i = 0; i < 64; ++i) {
        float4 kv = *(const float4*)(kl + i * 128 + op * 4);
        float2 c0 = *(const float2*)(xl + i * 32 + g * 2);
        float2 c1 = *(const float2*)(xl + i * 32 + (g + 8) * 2);
        a0r += kv.x * c0.x - kv.y * c0.y;  a0i += kv.x * c0.y + kv.y * c0.x;
        a1r += kv.z * c0.x - kv.w * c0.y;  a1i += kv.z * c0.y + kv.w * c0.x;
        b0r += kv.x * c1.x - kv.y * c1.y;  b0i += kv.x * c1.y + kv.y * c1.x;
        b1r += kv.z * c1.x - kv.w * c1.y;  b1i += kv.z * c1.y + kv.w * c1.x;
    }
    size_t base0 = ((((size_t)g       * KH + k2) * 68 + k1) * 64 + 2 * op) * 2;
    size_t base1 = ((((size_t)(g + 8) * KH + k2) * 68 + k1) * 64 + 2 * op) * 2;
    *(float4*)(Oc + base0) = make_float4(a0r, a0i, a1r, a1i);
    *(float4*)(Oc + base1) = make_float4(b0r, b0i, b1r, b1i);
}

// ---------------- stage 4: inverse column DFT ----------------
// Z[nl][p][k2][o] = sum_k1 Wi[p][k1] * O[nl][k2][k1][o]
__global__ __launch_bounds__(512) void k_inv_col(
        const float* __restrict__ O, const float* __restrict__ Wi,
        float* __restrict__ Z) {
    __shared__ float ol[68 * 128];       // 34 KB
    __shared__ float wih[34 * 136];      // 18.5 KB (this block's p-half)
    int lc = blockIdx.x / 1120;
    int rem = blockIdx.x % 1120;
    int ph = rem & 1;
    int rest = rem >> 1;
    int k2 = rest % KH, nl = rest / KH;
    int t = threadIdx.x;
    const float* Oc = O + (size_t)lc * CHS;
    float* Zc = Z + (size_t)lc * CHS;
    const float4* osrc = (const float4*)(Oc + ((size_t)nl * KH + k2) * 68 * 128);
    float4* ol4 = (float4*)ol;
    for (int e = t; e < 68 * 32; e += 512) ol4[e] = osrc[e];
    const float* wsrc = Wi + (size_t)ph * 34 * 136;
    for (int e = t; e < 34 * 136; e += 512) wih[e] = wsrc[e];
    __syncthreads();
    int o = t & 63, g = t >> 6;
    const float* oo_ = ol + o * 2;
    for (int j = 0; j < 5; ++j) {
        int pl = g + 8 * j;
        if (pl >= 34) break;
        int p = ph * 34 + pl;
        const float* w = wih + pl * 136;
        float ar = 0.f, ai = 0.f;
        #pragma unroll 17
        for (int k1 = 0; k1 < 68; k1 += 2) {
            float4 wv = *(const float4*)(w + 2 * k1);
            float2 q0 = *(const float2*)(oo_ + k1 * 128);
            float2 q1 = *(const float2*)(oo_ + k1 * 128 + 128);
            ar += wv.x * q0.x - wv.y * q0.y;
            ai += wv.x * q0.y + wv.y * q0.x;
            ar += wv.z * q1.x - wv.w * q1.y;
            ai += wv.z * q1.y + wv.w * q1.x;
        }
        *(float2*)(Zc + ((size_t)(nl * 68 + p) * KH + k2) * 128 + o * 2)
            = make_float2(ar, ai);
    }
}

// ---------------- stage 5 (fused): inverse row DFT + overlap-add ------------
__global__ __launch_bounds__(1024) void k_fused_inv(
        const float* __restrict__ Z, const float* __restrict__ Wg,
        const float* __restrict__ bias, float* __restrict__ out, int c0) {
    __shared__ float zs[6 * 4480];       // up to 6 slices  107.5 KB
    __shared__ float wg[68 * 70];        // 19 KB
    int lc = blockIdx.x >> 9;
    int rem = blockIdx.x & 511;
    int y  = rem >> 1;
    int x0 = (rem & 1) << 7;
    int b  = c0 + lc;
    int t  = threadIdx.x;
    const float* Zc = Z + (size_t)lc * CHS;

    int tr_hi = min(3, y / 66);
    int tr_lo = (y <= 67) ? 0 : (y - 2) / 66;
    int tcs = (x0 <= 67) ? 0 : (x0 - 2) / 66;
    int tce = min(3, (x0 + 127) / 66);
    int ntr = tr_hi - tr_lo + 1;
    int ntc = tce - tcs + 1;

    int total4 = ntr * ntc * 1120;
    float4* zs4 = (float4*)zs;
    for (int e = t; e < total4; e += 1024) {
        int sl = e / 1120, r4 = e % 1120;
        int tr = tr_lo + sl / ntc, tc = tcs + sl % ntc;
        int nl = tr * 4 + tc;
        int p  = y - 66 * tr;
        zs4[e] = ((const float4*)(Zc + ((size_t)(nl * 68 + p)) * 4480))[r4];
    }
    for (int e = t; e < 4760; e += 1024) wg[e] = Wg[e];
    __syncthreads();

    int op = t & 31;
    int xr = t >> 5;
    float bv0 = bias[2 * op], bv1 = bias[2 * op + 1];
    float acc00 = 0.f, acc01 = 0.f, acc10 = 0.f, acc11 = 0.f;
    float acc20 = 0.f, acc21 = 0.f, acc30 = 0.f, acc31 = 0.f;
    int cnt0 = 0, cnt1 = 0, cnt2 = 0, cnt3 = 0;

    for (int tr = tr_lo; tr <= tr_hi; ++tr) {
        for (int tc = tcs; tc <= tce; ++tc) {
            const float* zb = zs + (((tr - tr_lo) * ntc) + (tc - tcs)) * 4480 + op * 4;
            int qb = x0 + xr - 66 * tc;
            bool v0 = (qb      >= 0) && (qb      < 68);
            bool v1 = (qb + 32 >= 0) && (qb + 32 < 68);
            bool v2 = (qb + 64 >= 0) && (qb + 64 < 68);
            bool v3 = (qb + 96 >= 0) && (qb + 96 < 68);
            const float* w0 = wg + qb * 70;
            const float* w1 = w0 + 32 * 70;
            const float* w2 = w0 + 64 * 70;
            const float* w3 = w0 + 96 * 70;
            for (int k2 = 0; k2 < KH; ++k2) {
                float4 zv = *(const float4*)(zb + k2 * 128);
                if (v0) { float2 wv = *(const float2*)(w0 + 2 * k2);
                    acc00 += zv.x * wv.x - zv.y * wv.y;
                    acc01 += zv.z * wv.x - zv.w * wv.y; }
                if (v1) { float2 wv = *(const float2*)(w1 + 2 * k2);
                    acc10 += zv.x * wv.x - zv.y * wv.y;
                    acc11 += zv.z * wv.x - zv.w * wv.y; }
                if (v2) { float2 wv = *(const float2*)(w2 + 2 * k2);
                    acc20 += zv.x * wv.x - zv.y * wv.y;
                    acc21 += zv.z * wv.x - zv.w * wv.y; }
                if (v3) { float2 wv = *(const float2*)(w3 + 2 * k2);
                    acc30 += zv.x * wv.x - zv.y * wv.y;
                    acc31 += zv.z * wv.x - zv.w * wv.y; }
            }
            cnt0 += v0; cnt1 += v1; cnt2 += v2; cnt3 += v3;
        }
    }
    float* ob = out + (((size_t)(b * 256 + y)) * 256 + x0 + xr) * 64 + op * 2;
    *(float2*)(ob)             = make_float2(acc00 + cnt0 * bv0, acc01 + cnt0 * bv1);
    *(float2*)(ob + 32 * 64)   = make_float2(acc10 + cnt1 * bv0, acc11 + cnt1 * bv1);
    *(float2*)(ob + 64 * 64)   = make_float2(acc20 + cnt2 * bv0, acc21 + cnt2 * bv1);
    *(float2*)(ob + 96 * 64)   = make_float2(acc30 + cnt3 * bv0, acc31 + cnt3 * bv1);
}

extern "C" void kernel_launch(void* const* d_in, const int* in_sizes, int n_in,
                              void* d_out, int out_size, void* d_ws, size_t ws_size,
                              hipStream_t stream) {
    const float* x    = (const float*)d_in[0];
    const float* kr   = (const float*)d_in[1];
    const float* ki   = (const float*)d_in[2];
    const float* bias = (const float*)d_in[3];
    float* out = (float*)d_out;
    float* ws  = (float*)d_ws;

    // chunks per launch group (each chunk = 16 tiles = 1 image)
    int useKt = 1;
    int CH = 8;
    while (CH > 1 && (22720ull + KT_FLOATS + 2ull * CH * CHS) * 4ull > ws_size) CH >>= 1;
    if ((22720ull + KT_FLOATS + 2ull * CH * CHS) * 4ull > ws_size) {
        useKt = 0;
        CH = 8;
        while (CH > 1 && (22720ull + 2ull * CH * CHS) * 4ull > ws_size) CH >>= 1;
    }

    float* Wf   = ws;                          // 8704 floats
    float* Wi   = ws + 8704;                   // 9248 floats
    float* Wg   = ws + 17952;                  // 4760 floats
    float* Kt   = ws + 22720;                  // KT_FLOATS (if useKt)
    float* bufA = Kt + (useKt ? KT_FLOATS : 0);   // Y then O
    float* bufB = bufA + (size_t)CH * CHS;        // X then Z

    k_twiddle<<<1, 256, 0, stream>>>(ws);
    if (useKt)
        k_ktrans<<<68 * 64, 256, 0, stream>>>(kr, ki, Kt);

    for (int s = 0; s < 8; s += CH) {
        k_fwd_row<<<CH * 1024, 256, 0, stream>>>(x, Wf, bufA, s);
        k_fwd_col<<<CH * 512, 256, 0, stream>>>(bufA, Wf, bufB);
        k_mix<<<CH * 2380, 256, 0, stream>>>(bufB, Kt, kr, ki, bufA, useKt);
        k_inv_col<<<CH * 1120, 512, 0, stream>>>(bufA, Wi, bufB);
        k_fused_inv<<<CH * 512, 1024, 0, stream>>>(bufB, Wg, bias, out, s);
    }
}